// Round 14
// baseline (119.277 us; speedup 1.0000x reference)
//
#include <hip/hip_runtime.h>
#include <hip/hip_bf16.h>
#include <stdint.h>
#include <stddef.h>

// MMD via single signed 2N x 2N RBF gram, lower triangle only.
// Round 20: VALU diet + burst de-phasing on the r15 skeleton (best: 52.4 us).
// r19 (counted vmcnt/setprio/depth-2) was NULL -> sync structure exonerated.
// Measured VALU ~800 cyc/wave-slice (largest pipe), ~450 of it overhead:
//  1. incremental slice addressing (running colByte; ~4 ops vs ~30+branches)
//  2. f32x2 packed epilogue (v_pk_fma_f32 halves the 64 fma instrs)
//  3. per-wave col-group rotation (nt+wave)&3: the 4 waves read disjoint
//     LDS regions at any instant -> post-barrier LDS burst smoothed
//  4. per-wave atomics (no wsum LDS reduce/barrier); LDS exactly 32768 B
// Sync: r15's single __syncthreads per slice (best measured).

#define N_PTS   8192
#define DIM     256
#define TWO_N   16384

#define AS1 __attribute__((address_space(1)))
#define AS3 __attribute__((address_space(3)))

typedef __attribute__((ext_vector_type(2))) float f32x2;
typedef __attribute__((ext_vector_type(4))) float f32x4;
typedef __attribute__((ext_vector_type(4))) int   i32x4;
typedef __attribute__((ext_vector_type(8))) int   i32x8;

// ---------------------------------------------------------------------------
// Prep: fp32 -> fp8 e4m3 (row-major) + c2-scaled fp32 row norms; zero partials.
// n2[row] = c2 * |z_row|^2, c2 = -log2e/sigma (epilogue adds directly).
// ---------------------------------------------------------------------------
__global__ __launch_bounds__(256) void mmd_prep(const float* __restrict__ X,
                                                const float* __restrict__ Y,
                                                const int* __restrict__ sigmap,
                                                unsigned char* __restrict__ Zf8,
                                                float* __restrict__ n2,
                                                float* __restrict__ part) {
    if (blockIdx.x == 0 && threadIdx.x < 64) part[threadIdx.x] = 0.0f;

    const int wave = threadIdx.x >> 6;
    const int lane = threadIdx.x & 63;
    const int row  = blockIdx.x * 4 + wave;          // 0 .. TWO_N-1

    const float* src = (row < N_PTS) ? (X + (size_t)row * DIM)
                                     : (Y + (size_t)(row - N_PTS) * DIM);
    float4 v = ((const float4*)src)[lane];           // 64 lanes x 4 = 256

    float s = v.x * v.x + v.y * v.y + v.z * v.z + v.w * v.w;
#pragma unroll
    for (int off = 32; off; off >>= 1) s += __shfl_down(s, off, 64);
    if (lane == 0) {
        const float c2 = -1.4426950408889634f / (float)(*sigmap);
        n2[row] = c2 * s;
    }

    const int p01 = __builtin_amdgcn_cvt_pk_fp8_f32(v.x, v.y, 0, false);
    const int p23 = __builtin_amdgcn_cvt_pk_fp8_f32(v.z, v.w, 0, false);
    const unsigned int pk = ((unsigned)p01 & 0xffffu) | ((unsigned)p23 << 16);
    *(unsigned int*)(Zf8 + (size_t)row * DIM + (size_t)lane * 4) = pk;
}

// ---------------------------------------------------------------------------
// Main. grid = 1024: p = bid>>4 (row pair {p, 127-p}), cc = bid&15.
// Slice s: colByte = bc*32768 + h*16384 advanced incrementally
// (+16384 h0->h1, +507904 h1->next tile, reset to ccB at segment switch).
// 4 waves in 4x1 (wave owns 32 rows); wave w touches col-group (nt+w)&3.
// Per slice: [eb exp2][syncthreads][stage next][16 MFMA 16x16x128 MX-fp8]
// [packed epilogue]. LDS col = 256 B = 16 slots; slot s = chunk s^(c&15).
// ---------------------------------------------------------------------------
__global__ __launch_bounds__(256, 4) void mmd_main(const unsigned char* __restrict__ Zf8,
                                                   const float* __restrict__ n2,
                                                   const int* __restrict__ sigmap,
                                                   float* __restrict__ part) {
    __shared__ char smem_b[32768];   // 2 x 16 KB col-slice buffers

    const int bid = (int)blockIdx.x;
    const int p   = bid >> 4;        // 0..63
    const int cc  = bid & 15;
    const int r0  = p;               // row tile 0..63
    const int r1  = 127 - p;         // row tile 64..127

    const int nT0 = (cc <= r0) ? (((r0 - cc) >> 4) + 1) : 0;
    const int nT1 = ((r1 - cc) >> 4) + 1;
    const int nS0 = nT0 * 2;
    const int nS  = nS0 + nT1 * 2;

    const int t    = threadIdx.x;
    const int wave = t >> 6;         // 0..3: 32-row group
    const int lane = t & 63;
    const int g    = lane >> 4;      // k-quad
    const int ml   = lane & 15;

    const float m2 = 2.8853900817779268f / (float)(*sigmap);   // 2*log2e/sigma
    const f32x2 m2v = {m2, m2};
    const int   SC = 0x7f7f7f7f;     // E8M0 unit scales (2^0)

    // ---- staging invariants: 1024 16B chunks / 256 threads = 4 per thread
    const int gbase = (t >> 4) * 256 + (((t & 15) ^ (t >> 4)) * 16);
    const int lbase = t * 16;

    // ---- rotated col-group offsets (wave w starts at group w) ----
    int ntB[4], ntE[4];
#pragma unroll
    for (int nt = 0; nt < 4; ++nt) {
        const int n2v = (nt + wave) & 3;
        ntB[nt] = n2v * 4096;        // LDS byte offset of col group
        ntE[nt] = n2v * 16 + ml;     // n2 column offset
    }

    // ---- bf ds_read bases (col component = ml*256) ----
    int rb0[2], rb1[2];
#pragma unroll
    for (int kc = 0; kc < 2; ++kc) {
        rb0[kc] = ml * 256 + (((kc * 8 + g * 2)     ^ ml) * 16);
        rb1[kc] = ml * 256 + (((kc * 8 + g * 2 + 1) ^ ml) * 16);
    }

    // ---- A-panel registers (reloaded once at row switch) ----
    i32x8 af[2][2];
    f32x2 ai01[2], ai23[2];
    auto loadA = [&](int rowTile) {
        const int rowBase = rowTile * 128;
#pragma unroll
        for (int mt = 0; mt < 2; ++mt) {
            const unsigned char* rp =
                Zf8 + (size_t)(rowBase + wave * 32 + mt * 16 + ml) * 256 + g * 32;
#pragma unroll
            for (int kc = 0; kc < 2; ++kc) {
                union { i32x4 h[2]; i32x8 v; } u;
                u.h[0] = *(const i32x4*)(rp + kc * 128);
                u.h[1] = *(const i32x4*)(rp + kc * 128 + 16);
                af[mt][kc] = u.v;
            }
        }
#pragma unroll
        for (int mt = 0; mt < 2; ++mt) {
            const float* ap = n2 + rowBase + wave * 32 + mt * 16 + g * 4;
            ai01[mt][0] = ap[0]; ai01[mt][1] = ap[1];
            ai23[mt][0] = ap[2]; ai23[mt][1] = ap[3];
        }
    };

    const int firstRow = nT0 ? r0 : r1;
    loadA(firstRow);

    const f32x4 zacc = {0.0f, 0.0f, 0.0f, 0.0f};
    const int ccB = cc << 15;        // cc * 32768

    auto stageTo = [&](char* dstBuf, int srcByte) {
        const unsigned char* sb = Zf8 + (size_t)srcByte + gbase;
#pragma unroll
        for (int i = 0; i < 4; ++i)
            __builtin_amdgcn_global_load_lds((const AS1 void*)(sb + i * 4096),
                                             (AS3 void*)(dstBuf + i * 4096 + lbase), 16, 0, 0);
    };

    // ---- prologue: stage slice 0 into buffer 0 ----
    int colByte = ccB;
    stageTo(smem_b, colByte);

    float block_acc = 0.0f;
    int cur = 0;

    for (int s = 0; s < nS; ++s) {
        if (nT0 && s == nS0) loadA(r1);                  // row switch, once
        const int rowT = (s < nS0) ? r0 : r1;
        const int bc     = colByte >> 15;                // tile column index
        const int colIdx = colByte >> 8;                 // column (elements)

        // per-slice multiplicative column factors (pre-barrier, overlaps)
        float eb[4];
#pragma unroll
        for (int nt = 0; nt < 4; ++nt)
            eb[nt] = __builtin_amdgcn_exp2f(n2[colIdx + ntE[nt]]);

        // incremental next-slice byte offset (~4 ops, replaces sliceCol)
        const int sN = s + 1;
        int stageByte = colByte + ((s & 1) ? 507904 : 16384);
        if (sN == nS0) stageByte = ccB;

        __syncthreads();             // slice s staged in buf cur; cur^1 free

        // ---- stage next slice into the other buffer (overlaps compute) ----
        if (sN < nS) stageTo(smem_b + (cur ^ 1) * 16384, stageByte);

        // ---- compute: 4 nt (rotated per wave) x (2 mt x 2 kc) MFMA ----
        const char* buf = smem_b + cur * 16384;
        f32x4 acc[2][4];
#pragma unroll
        for (int nt = 0; nt < 4; ++nt) {
#pragma unroll
            for (int kc = 0; kc < 2; ++kc) {
                union { i32x4 hh[2]; i32x8 v; } u;
                u.hh[0] = *(const i32x4*)(buf + ntB[nt] + rb0[kc]);
                u.hh[1] = *(const i32x4*)(buf + ntB[nt] + rb1[kc]);
                const i32x8 bf = u.v;
#pragma unroll
                for (int mt = 0; mt < 2; ++mt)
                    acc[mt][nt] = __builtin_amdgcn_mfma_scale_f32_16x16x128_f8f6f4(
                        af[mt][kc], bf, (kc == 0) ? zacc : acc[mt][nt],
                        0, 0, 0, SC, 0, SC);
            }
        }

        // ---- packed epilogue: v_pk_fma_f32 + exp2 ----
        f32x2 ts01 = {0.0f, 0.0f}, ts23 = {0.0f, 0.0f};
#pragma unroll
        for (int mt = 0; mt < 2; ++mt)
#pragma unroll
            for (int nt = 0; nt < 4; ++nt) {
                const f32x2 lo = {acc[mt][nt][0], acc[mt][nt][1]};
                const f32x2 hi = {acc[mt][nt][2], acc[mt][nt][3]};
                const f32x2 tlo = __builtin_elementwise_fma(lo, m2v, ai01[mt]);
                const f32x2 thi = __builtin_elementwise_fma(hi, m2v, ai23[mt]);
                const f32x2 ev  = {eb[nt], eb[nt]};
                const f32x2 elo = {__builtin_amdgcn_exp2f(tlo[0]),
                                   __builtin_amdgcn_exp2f(tlo[1])};
                const f32x2 ehi = {__builtin_amdgcn_exp2f(thi[0]),
                                   __builtin_amdgcn_exp2f(thi[1])};
                ts01 = __builtin_elementwise_fma(elo, ev, ts01);
                ts23 = __builtin_elementwise_fma(ehi, ev, ts23);
            }
        const float tsum = (ts01[0] + ts01[1]) + (ts23[0] + ts23[1]);

        const float sgn = ((bc < 64) == (rowT < 64)) ? 1.0f : -1.0f;
        const float w   = (bc == rowT) ? sgn : 2.0f * sgn;   // symmetry weight
        block_acc = fmaf(w, tsum, block_acc);

        colByte = stageByte;
        cur ^= 1;
    }

    // ---- wave reduction + per-wave hashed atomic (no LDS reduce) ----
    float s = block_acc;
#pragma unroll
    for (int off = 32; off; off >>= 1) s += __shfl_down(s, off, 64);
    if (lane == 0)
        atomicAdd(part + (bid & 63), s);
}

// ---------------------------------------------------------------------------
// Finish: reduce 64 partials, scale, write scalar output.
// ---------------------------------------------------------------------------
__global__ __launch_bounds__(64) void mmd_finish(const float* __restrict__ part,
                                                 float* __restrict__ out) {
    const int lane = threadIdx.x & 63;
    float s = part[lane];
#pragma unroll
    for (int off = 32; off; off >>= 1) s += __shfl_down(s, off, 64);
    if (lane == 0) out[0] = s * (1.0f / 67108864.0f);
}

// ---------------------------------------------------------------------------
extern "C" void kernel_launch(void* const* d_in, const int* in_sizes, int n_in,
                              void* d_out, int out_size, void* d_ws, size_t ws_size,
                              hipStream_t stream) {
    const float* X      = (const float*)d_in[0];
    const float* Y      = (const float*)d_in[1];
    const int*   sigmap = (const int*)d_in[2];
    float*       out    = (float*)d_out;

    unsigned char* Zf8  = (unsigned char*)d_ws;                       // 4 MB
    float*         n2   = (float*)((char*)d_ws + (size_t)TWO_N * DIM);
    float*         part = n2 + TWO_N;                                 // 64 floats

    mmd_prep<<<TWO_N / 4, 256, 0, stream>>>(X, Y, sigmap, Zf8, n2, part);
    mmd_main<<<64 * 16, 256, 0, stream>>>(Zf8, n2, sigmap, part);
    mmd_finish<<<1, 64, 0, stream>>>(part, out);
}

// Round 15
// 114.889 us; speedup vs baseline: 1.0382x; 1.0382x over previous
//
#include <hip/hip_runtime.h>
#include <hip/hip_bf16.h>
#include <stdint.h>
#include <stddef.h>

// MMD via single signed 2N x 2N RBF gram, lower triangle only.
// Round 21: consolidation on the r15 skeleton (best measured main: 52.4 us).
// Changes vs r15, each individually safe: (1) r20's incremental slice
// addressing (running colByte, ~4 ops vs ~30+branch sliceCol recompute) —
// WITHOUT r20's rotation / packed-epilogue confounders; (2) dead code
// removed. Session state: 7 structural variants all land 52-55 us; no pipe
// >45%; latency-bound at 4 waves/SIMD (reg-file-capped). This is the
// best-known config + cheap VALU cleanup; if within noise, plateau declared.

#define N_PTS   8192
#define DIM     256
#define TWO_N   16384

#define AS1 __attribute__((address_space(1)))
#define AS3 __attribute__((address_space(3)))

typedef __attribute__((ext_vector_type(4))) float f32x4;
typedef __attribute__((ext_vector_type(4))) int   i32x4;
typedef __attribute__((ext_vector_type(8))) int   i32x8;

// ---------------------------------------------------------------------------
// Prep: fp32 -> fp8 e4m3 (row-major) + c2-scaled fp32 row norms; zero partials.
// n2[row] = c2 * |z_row|^2, c2 = -log2e/sigma (epilogue adds directly).
// ---------------------------------------------------------------------------
__global__ __launch_bounds__(256) void mmd_prep(const float* __restrict__ X,
                                                const float* __restrict__ Y,
                                                const int* __restrict__ sigmap,
                                                unsigned char* __restrict__ Zf8,
                                                float* __restrict__ n2,
                                                float* __restrict__ part) {
    if (blockIdx.x == 0 && threadIdx.x < 64) part[threadIdx.x] = 0.0f;

    const int wave = threadIdx.x >> 6;
    const int lane = threadIdx.x & 63;
    const int row  = blockIdx.x * 4 + wave;          // 0 .. TWO_N-1

    const float* src = (row < N_PTS) ? (X + (size_t)row * DIM)
                                     : (Y + (size_t)(row - N_PTS) * DIM);
    float4 v = ((const float4*)src)[lane];           // 64 lanes x 4 = 256

    float s = v.x * v.x + v.y * v.y + v.z * v.z + v.w * v.w;
#pragma unroll
    for (int off = 32; off; off >>= 1) s += __shfl_down(s, off, 64);
    if (lane == 0) {
        const float c2 = -1.4426950408889634f / (float)(*sigmap);
        n2[row] = c2 * s;
    }

    const int p01 = __builtin_amdgcn_cvt_pk_fp8_f32(v.x, v.y, 0, false);
    const int p23 = __builtin_amdgcn_cvt_pk_fp8_f32(v.z, v.w, 0, false);
    const unsigned int pk = ((unsigned)p01 & 0xffffu) | ((unsigned)p23 << 16);
    *(unsigned int*)(Zf8 + (size_t)row * DIM + (size_t)lane * 4) = pk;
}

// ---------------------------------------------------------------------------
// Main. grid = 1024: p = bid>>4 (row pair {p, 127-p}), cc = bid&15.
// For each owned row r, tiles bc = cc, cc+16, .. <= r; 2 col-slices per tile
// (h=0,1: cols bc*128+h*64..+64, full K=256). Slice address advanced
// incrementally: colByte += (s&1) ? 507904 : 16384, reset to ccB at segment
// switch (nS0 is even, so h = s&1 holds globally). 4 waves in 4x1; wave owns
// rows rowT*128 + wave*32 .. +32. Per slice: [eb exp2][syncthreads]
// [stage next][16 MFMA 16x16x128 MX-fp8][epilogue]. LDS col = 256 B =
// 16 x 16B slots; slot s of col c holds global chunk s ^ (c&15).
// ---------------------------------------------------------------------------
__global__ __launch_bounds__(256, 4) void mmd_main(const unsigned char* __restrict__ Zf8,
                                                   const float* __restrict__ n2,
                                                   const int* __restrict__ sigmap,
                                                   float* __restrict__ part) {
    __shared__ char smem_b[32768];   // 2 x 16 KB col-slice buffers
    __shared__ float wsum[4];

    const int bid = (int)blockIdx.x;
    const int p   = bid >> 4;        // 0..63
    const int cc  = bid & 15;
    const int r0  = p;               // row tile 0..63
    const int r1  = 127 - p;         // row tile 64..127

    const int nT0 = (cc <= r0) ? (((r0 - cc) >> 4) + 1) : 0;
    const int nT1 = ((r1 - cc) >> 4) + 1;
    const int nS0 = nT0 * 2;         // even
    const int nS  = nS0 + nT1 * 2;

    const int t    = threadIdx.x;
    const int wave = t >> 6;         // 0..3: 32-row group
    const int lane = t & 63;
    const int g    = lane >> 4;      // k-quad
    const int ml   = lane & 15;

    const float m2 = 2.8853900817779268f / (float)(*sigmap);   // 2*log2e/sigma
    const int   SC = 0x7f7f7f7f;     // E8M0 unit scales (2^0)

    // ---- staging invariants: 1024 16B chunks / 256 threads = 4 per thread
    const int gbase = (t >> 4) * 256 + (((t & 15) ^ (t >> 4)) * 16);
    const int lbase = t * 16;

    // ---- bf ds_read bases (col = nt*16 + ml within slice) ----
    int rb0[2], rb1[2];
#pragma unroll
    for (int kc = 0; kc < 2; ++kc) {
        rb0[kc] = ml * 256 + (((kc * 8 + g * 2)     ^ ml) * 16);
        rb1[kc] = ml * 256 + (((kc * 8 + g * 2 + 1) ^ ml) * 16);
    }

    // ---- A-panel registers (reloaded once at row switch) ----
    i32x8 af[2][2];
    float a_i[2][4];
    auto loadA = [&](int rowTile) {
        const int rowBase = rowTile * 128;
#pragma unroll
        for (int mt = 0; mt < 2; ++mt) {
            const unsigned char* rp =
                Zf8 + (size_t)(rowBase + wave * 32 + mt * 16 + ml) * 256 + g * 32;
#pragma unroll
            for (int kc = 0; kc < 2; ++kc) {
                union { i32x4 h[2]; i32x8 v; } u;
                u.h[0] = *(const i32x4*)(rp + kc * 128);
                u.h[1] = *(const i32x4*)(rp + kc * 128 + 16);
                af[mt][kc] = u.v;
            }
        }
#pragma unroll
        for (int mt = 0; mt < 2; ++mt)
#pragma unroll
            for (int rr = 0; rr < 4; ++rr)
                a_i[mt][rr] = n2[rowBase + wave * 32 + mt * 16 + g * 4 + rr];
    };

    const int firstRow = nT0 ? r0 : r1;
    loadA(firstRow);

    const f32x4 zacc = {0.0f, 0.0f, 0.0f, 0.0f};
    const int ccB = cc << 15;        // cc * 32768

    auto stageTo = [&](char* dstBuf, int srcByte) {
        const unsigned char* sb = Zf8 + (size_t)srcByte + gbase;
#pragma unroll
        for (int i = 0; i < 4; ++i)
            __builtin_amdgcn_global_load_lds((const AS1 void*)(sb + i * 4096),
                                             (AS3 void*)(dstBuf + i * 4096 + lbase), 16, 0, 0);
    };

    // ---- prologue: stage slice 0 into buffer 0 ----
    int colByte = ccB;
    stageTo(smem_b, colByte);

    float block_acc = 0.0f;
    int cur = 0;

    for (int s = 0; s < nS; ++s) {
        if (nT0 && s == nS0) loadA(r1);              // row switch, once
        const int rowT   = (s < nS0) ? r0 : r1;
        const int bc     = colByte >> 15;            // tile column index
        const int colIdx = colByte >> 8;             // column (elements)

        // per-slice multiplicative column factors (pre-barrier, overlaps)
        float eb[4];
#pragma unroll
        for (int nt = 0; nt < 4; ++nt)
            eb[nt] = __builtin_amdgcn_exp2f(n2[colIdx + nt * 16 + ml]);

        // incremental next-slice byte offset (replaces sliceCol recompute)
        const int sN = s + 1;
        int stageByte = colByte + ((s & 1) ? 507904 : 16384);
        if (sN == nS0) stageByte = ccB;

        __syncthreads();             // slice s staged in buf cur; cur^1 free

        // ---- stage next slice into the other buffer (overlaps compute) ----
        if (sN < nS) stageTo(smem_b + (cur ^ 1) * 16384, stageByte);

        // ---- compute: 4 nt x (2 mt x 2 kc) MFMA, full-K per slice ----
        const char* buf = smem_b + cur * 16384;
        f32x4 acc[2][4];
#pragma unroll
        for (int nt = 0; nt < 4; ++nt) {
#pragma unroll
            for (int kc = 0; kc < 2; ++kc) {
                union { i32x4 hh[2]; i32x8 v; } u;
                u.hh[0] = *(const i32x4*)(buf + nt * 4096 + rb0[kc]);
                u.hh[1] = *(const i32x4*)(buf + nt * 4096 + rb1[kc]);
                const i32x8 bf = u.v;
#pragma unroll
                for (int mt = 0; mt < 2; ++mt)
                    acc[mt][nt] = __builtin_amdgcn_mfma_scale_f32_16x16x128_f8f6f4(
                        af[mt][kc], bf, (kc == 0) ? zacc : acc[mt][nt],
                        0, 0, 0, SC, 0, SC);
            }
        }

        // ---- epilogue for this slice ----
        float ts0 = 0.0f, ts1 = 0.0f, ts2 = 0.0f, ts3 = 0.0f;
#pragma unroll
        for (int mt = 0; mt < 2; ++mt)
#pragma unroll
            for (int nt = 0; nt < 4; ++nt) {
                const float e = eb[nt];
                ts0 = fmaf(__builtin_amdgcn_exp2f(fmaf(acc[mt][nt][0], m2, a_i[mt][0])), e, ts0);
                ts1 = fmaf(__builtin_amdgcn_exp2f(fmaf(acc[mt][nt][1], m2, a_i[mt][1])), e, ts1);
                ts2 = fmaf(__builtin_amdgcn_exp2f(fmaf(acc[mt][nt][2], m2, a_i[mt][2])), e, ts2);
                ts3 = fmaf(__builtin_amdgcn_exp2f(fmaf(acc[mt][nt][3], m2, a_i[mt][3])), e, ts3);
            }
        const float tsum = (ts0 + ts1) + (ts2 + ts3);

        const float sgn = ((bc < 64) == (rowT < 64)) ? 1.0f : -1.0f;
        const float w   = (bc == rowT) ? sgn : 2.0f * sgn;   // symmetry weight
        block_acc = fmaf(w, tsum, block_acc);

        colByte = stageByte;
        cur ^= 1;
    }

    // ---- block reduction + hashed atomic ----
    float s = block_acc;
#pragma unroll
    for (int off = 32; off; off >>= 1) s += __shfl_down(s, off, 64);
    if (lane == 0) wsum[wave] = s;
    __syncthreads();
    if (t == 0)
        atomicAdd(part + (bid & 63), wsum[0] + wsum[1] + wsum[2] + wsum[3]);
}

// ---------------------------------------------------------------------------
// Finish: reduce 64 partials, scale, write scalar output.
// ---------------------------------------------------------------------------
__global__ __launch_bounds__(64) void mmd_finish(const float* __restrict__ part,
                                                 float* __restrict__ out) {
    const int lane = threadIdx.x & 63;
    float s = part[lane];
#pragma unroll
    for (int off = 32; off; off >>= 1) s += __shfl_down(s, off, 64);
    if (lane == 0) out[0] = s * (1.0f / 67108864.0f);
}

// ---------------------------------------------------------------------------
extern "C" void kernel_launch(void* const* d_in, const int* in_sizes, int n_in,
                              void* d_out, int out_size, void* d_ws, size_t ws_size,
                              hipStream_t stream) {
    const float* X      = (const float*)d_in[0];
    const float* Y      = (const float*)d_in[1];
    const int*   sigmap = (const int*)d_in[2];
    float*       out    = (float*)d_out;

    unsigned char* Zf8  = (unsigned char*)d_ws;                       // 4 MB
    float*         n2   = (float*)((char*)d_ws + (size_t)TWO_N * DIM);
    float*         part = n2 + TWO_N;                                 // 64 floats

    mmd_prep<<<TWO_N / 4, 256, 0, stream>>>(X, Y, sigmap, Zf8, n2, part);
    mmd_main<<<64 * 16, 256, 0, stream>>>(Zf8, n2, sigmap, part);
    mmd_finish<<<1, 64, 0, stream>>>(part, out);
}